// Round 1
// baseline (27.988 us; speedup 1.0000x reference)
//
#include <hip/hip_runtime.h>

#define HALF_DT 0.005f   // DT/2, DT = 0.01

// ---------------------------------------------------------------------------
// Kernel 1: v = tanh(z0 @ W^T + bias), stored TRANSPOSED: v_ws[col*32 + b]
//   z0: (32, 512), W: (2047, 512), bias: (2047)
// Grid: 256 blocks x 256 threads. Each block handles 8 columns (W rows).
// W rows staged in LDS (16 KB) via coalesced float4; each thread computes one
// (b, col) dot product. LDS reads: 2 distinct addresses per wave (broadcast).
// ---------------------------------------------------------------------------
__global__ __launch_bounds__(256) void compute_v_kernel(
    const float* __restrict__ z0,
    const float* __restrict__ W,
    const float* __restrict__ bias,
    float* __restrict__ v_ws)
{
    __shared__ float Wl[8 * 512];   // 16 KB
    const int tid  = threadIdx.x;
    const int col0 = blockIdx.x * 8;

    // cooperative load: 8 rows x 512 floats = 1024 float4, 4 per thread
    #pragma unroll
    for (int j = 0; j < 4; ++j) {
        int t4  = tid + j * 256;      // float4 index within tile
        int row = t4 >> 7;            // / 128 float4 per row
        int rem = t4 & 127;
        int col = col0 + row;
        float4 val = make_float4(0.f, 0.f, 0.f, 0.f);
        if (col < 2047) val = reinterpret_cast<const float4*>(W)[col * 128 + rem];
        reinterpret_cast<float4*>(Wl)[t4] = val;
    }
    __syncthreads();

    const int b   = tid & 31;
    const int g   = tid >> 5;
    const int col = col0 + g;

    const float4* z4 = reinterpret_cast<const float4*>(z0 + b * 512);
    const float4* w4 = reinterpret_cast<const float4*>(Wl + g * 512);
    float acc = 0.f;
    #pragma unroll 8
    for (int k4 = 0; k4 < 128; ++k4) {
        float4 z = z4[k4];
        float4 w = w4[k4];
        acc += w.x * z.x + w.y * z.y + w.z * z.z + w.w * z.w;
    }

    if (col < 2047) {
        v_ws[col * 32 + b] = tanhf(acc + bias[col]);
    }
}

// ---------------------------------------------------------------------------
// Kernel 2: solve (I + N) x = rhs per batch, N tridiagonal with
//   N[i][i-1] = +HALF_DT*v[i-1],  N[i][i+1] = -HALF_DT*v[i]
//   rhs[i] = h[i] + HALF_DT*v[i]*h[i+1] - HALF_DT*v[i-1]*h[i-1]
// ||N||inf <= 0.01  =>  Neumann iteration x <- rhs - N x converges at 0.01/step.
// 6 iterations -> relative error ~1e-14 (threshold is 8.9e-2).
// Grid: 32 blocks (one per batch) x 512 threads, 4 rows/thread. LDS = 48 KB.
// ---------------------------------------------------------------------------
__global__ __launch_bounds__(512) void solve_kernel(
    const float* __restrict__ h,
    const float* __restrict__ v_ws,
    float* __restrict__ out)
{
    __shared__ float hl[2048];
    __shared__ float s [2048];   // s[i] = HALF_DT * v[i-1]  (0 at i=0)
    __shared__ float q [2048];   // q[i] = HALF_DT * v[i]    (0 at i=2047)
    __shared__ float r [2048];   // rhs
    __shared__ float xa[2048];
    __shared__ float xb[2048];

    const int b   = blockIdx.x;
    const int tid = threadIdx.x;

    #pragma unroll
    for (int j = 0; j < 4; ++j) {
        int i = tid + j * 512;
        hl[i] = h[b * 2048 + i];
        s[i]  = (i >= 1)   ? HALF_DT * v_ws[(i - 1) * 32 + b] : 0.f;
        q[i]  = (i < 2047) ? HALF_DT * v_ws[i * 32 + b]       : 0.f;
    }
    __syncthreads();

    #pragma unroll
    for (int j = 0; j < 4; ++j) {
        int i = tid + j * 512;
        float hm = (i >= 1)   ? hl[i - 1] : 0.f;
        float hp = (i < 2047) ? hl[i + 1] : 0.f;
        float rv = hl[i] + q[i] * hp - s[i] * hm;
        r[i]  = rv;
        xa[i] = rv;   // x0 = rhs
    }
    __syncthreads();

    float* x  = xa;
    float* xn = xb;
    for (int it = 0; it < 6; ++it) {
        #pragma unroll
        for (int j = 0; j < 4; ++j) {
            int i = tid + j * 512;
            float xm = (i >= 1)   ? x[i - 1] : 0.f;
            float xp = (i < 2047) ? x[i + 1] : 0.f;
            xn[i] = r[i] - s[i] * xm + q[i] * xp;
        }
        __syncthreads();
        float* t = x; x = xn; xn = t;
    }

    #pragma unroll
    for (int j = 0; j < 4; ++j) {
        int i = tid + j * 512;
        out[b * 2048 + i] = x[i];
    }
}

extern "C" void kernel_launch(void* const* d_in, const int* in_sizes, int n_in,
                              void* d_out, int out_size, void* d_ws, size_t ws_size,
                              hipStream_t stream) {
    const float* z0   = (const float*)d_in[0];   // (32, 512)
    const float* h    = (const float*)d_in[1];   // (32, 2048)
    const float* W    = (const float*)d_in[2];   // (2047, 512)
    const float* bias = (const float*)d_in[3];   // (2047,)
    float* out  = (float*)d_out;                 // (32, 2048)
    float* v_ws = (float*)d_ws;                  // 2047*32 floats = 262 KB

    compute_v_kernel<<<256, 256, 0, stream>>>(z0, W, bias, v_ws);
    solve_kernel<<<32, 512, 0, stream>>>(h, v_ws, out);
}

// Round 2
// 15.673 us; speedup vs baseline: 1.7857x; 1.7857x over previous
//
#include <hip/hip_runtime.h>

#define HALF_DT 0.005f   // DT/2, DT = 0.01

typedef __attribute__((ext_vector_type(8))) short short8;   // 8 x bf16 (4 VGPRs)
typedef __attribute__((ext_vector_type(4))) float f32x4;    // MFMA accumulator

// fp32 -> bf16 with round-to-nearest-even (bit trick)
static __device__ inline short f2bf(float f) {
    union { float f; unsigned u; } x; x.f = f;
    unsigned r = (x.u + 0x7fffu + ((x.u >> 16) & 1u)) >> 16;
    return (short)r;
}

// load 8 consecutive fp32 (32B, 16B-aligned) and convert to bf16x8 fragment
static __device__ inline short8 cvt8(const float* __restrict__ p) {
    float4 lo = *reinterpret_cast<const float4*>(p);
    float4 hi = *reinterpret_cast<const float4*>(p + 4);
    short8 r;
    r[0] = f2bf(lo.x); r[1] = f2bf(lo.y); r[2] = f2bf(lo.z); r[3] = f2bf(lo.w);
    r[4] = f2bf(hi.x); r[5] = f2bf(hi.y); r[6] = f2bf(hi.z); r[7] = f2bf(hi.w);
    return r;
}

// ---------------------------------------------------------------------------
// Kernel 1: v[b][col] = tanh(z0[b,:] . W[col,:] + bias[col]) via bf16 MFMA.
//   D = A (z0, M=16 batches) x B (W^T, N=16 cols), K=512 in 16 steps of 32.
//   Two accumulators cover batches 0-15 and 16-31; B-fragment reused.
//   All fragment loads are direct per-lane global float4 + in-lane cvt: no LDS.
//   A-frag: lane l holds A[m=l&15][k=8*(l>>4)+j]; B-frag: B[k][n=l&15] = W[col][k].
//   C/D:    lane l, reg r -> row m = 4*(l>>4)+r (batch), col n = l&15.
//   Output v_ws layout: [b][2048] (col-padded) -> 64B-coalesced stores,
//   and coalesced coefficient reads in the solve kernel.
// Grid: 128 blocks x 64 threads (16 cols/block; last block store-guarded).
// ---------------------------------------------------------------------------
__global__ __launch_bounds__(64) void v_mfma_kernel(
    const float* __restrict__ z0,    // (32, 512)
    const float* __restrict__ W,     // (2047, 512)
    const float* __restrict__ bias,  // (2047,)
    float* __restrict__ v_ws)        // (32, 2048)
{
    const int lane = threadIdx.x;
    const int m    = lane & 15;
    const int q    = lane >> 4;          // 0..3
    const int col  = blockIdx.x * 16 + m;
    const int wcol = (col < 2046) ? col : 2046;   // clamp load row (guard store)

    const float* zA0 = z0 + m * 512 + 8 * q;          // batch m
    const float* zA1 = z0 + (m + 16) * 512 + 8 * q;   // batch m+16
    const float* wB  = W + wcol * 512 + 8 * q;

    f32x4 acc0 = {0.f, 0.f, 0.f, 0.f};
    f32x4 acc1 = {0.f, 0.f, 0.f, 0.f};

    #pragma unroll 4
    for (int k0 = 0; k0 < 512; k0 += 32) {
        short8 a0 = cvt8(zA0 + k0);
        short8 a1 = cvt8(zA1 + k0);
        short8 bb = cvt8(wB + k0);
        acc0 = __builtin_amdgcn_mfma_f32_16x16x32_bf16(a0, bb, acc0, 0, 0, 0);
        acc1 = __builtin_amdgcn_mfma_f32_16x16x32_bf16(a1, bb, acc1, 0, 0, 0);
    }

    if (col < 2047) {
        const float bv = bias[col];
        #pragma unroll
        for (int r = 0; r < 4; ++r) {
            const int b = 4 * q + r;
            v_ws[b * 2048 + col]        = tanhf(acc0[r] + bv);
            v_ws[(b + 16) * 2048 + col] = tanhf(acc1[r] + bv);
        }
    }
}

// ---------------------------------------------------------------------------
// Kernel 2: solve (I + N) x = rhs per batch, N tridiagonal with
//   N[i][i-1] = +HALF_DT*v[i-1],  N[i][i+1] = -HALF_DT*v[i]
//   rhs[i] = h[i] + HALF_DT*v[i]*h[i+1] - HALF_DT*v[i-1]*h[i-1]
// ||N||inf <= 0.01 => Neumann iteration x <- rhs - N x; 4 iters -> err ~1e-10.
// v_ws now [b][2048]: coefficient loads are coalesced 8KB streams.
// Grid: 32 blocks (one per batch) x 512 threads, 4 rows/thread.
// ---------------------------------------------------------------------------
__global__ __launch_bounds__(512) void solve_kernel(
    const float* __restrict__ h,
    const float* __restrict__ v_ws,
    float* __restrict__ out)
{
    __shared__ float hl[2048];
    __shared__ float s [2048];   // s[i] = HALF_DT * v[i-1]  (0 at i=0)
    __shared__ float q [2048];   // q[i] = HALF_DT * v[i]    (0 at i=2047)
    __shared__ float r [2048];   // rhs
    __shared__ float xa[2048];
    __shared__ float xb[2048];

    const int b   = blockIdx.x;
    const int tid = threadIdx.x;
    const float* __restrict__ vrow = v_ws + b * 2048;

    #pragma unroll
    for (int j = 0; j < 4; ++j) {
        int i = tid + j * 512;
        hl[i] = h[b * 2048 + i];
        s[i]  = (i >= 1)   ? HALF_DT * vrow[i - 1] : 0.f;
        q[i]  = (i < 2047) ? HALF_DT * vrow[i]     : 0.f;
    }
    __syncthreads();

    #pragma unroll
    for (int j = 0; j < 4; ++j) {
        int i = tid + j * 512;
        float hm = (i >= 1)   ? hl[i - 1] : 0.f;
        float hp = (i < 2047) ? hl[i + 1] : 0.f;
        float rv = hl[i] + q[i] * hp - s[i] * hm;
        r[i]  = rv;
        xa[i] = rv;   // x0 = rhs
    }
    __syncthreads();

    float* x  = xa;
    float* xn = xb;
    for (int it = 0; it < 4; ++it) {
        #pragma unroll
        for (int j = 0; j < 4; ++j) {
            int i = tid + j * 512;
            float xm = (i >= 1)   ? x[i - 1] : 0.f;
            float xp = (i < 2047) ? x[i + 1] : 0.f;
            xn[i] = r[i] - s[i] * xm + q[i] * xp;
        }
        __syncthreads();
        float* t = x; x = xn; xn = t;
    }

    #pragma unroll
    for (int j = 0; j < 4; ++j) {
        int i = tid + j * 512;
        out[b * 2048 + i] = x[i];
    }
}

extern "C" void kernel_launch(void* const* d_in, const int* in_sizes, int n_in,
                              void* d_out, int out_size, void* d_ws, size_t ws_size,
                              hipStream_t stream) {
    const float* z0   = (const float*)d_in[0];   // (32, 512)
    const float* h    = (const float*)d_in[1];   // (32, 2048)
    const float* W    = (const float*)d_in[2];   // (2047, 512)
    const float* bias = (const float*)d_in[3];   // (2047,)
    float* out  = (float*)d_out;                 // (32, 2048)
    float* v_ws = (float*)d_ws;                  // (32, 2048) floats = 256 KB

    v_mfma_kernel<<<128, 64, 0, stream>>>(z0, W, bias, v_ws);
    solve_kernel <<<32, 512, 0, stream>>>(h, v_ws, out);
}